// Round 10
// baseline (273.022 us; speedup 1.0000x reference)
//
#include <hip/hip_runtime.h>
#include <hip/hip_bf16.h>

typedef __attribute__((ext_vector_type(8))) short  short8;
typedef __attribute__((ext_vector_type(4))) float  floatx4;

constexpr int DIN = 100;
constexpr int H   = 64;
constexpr int G   = 10;
constexpr int NH  = 5;
constexpr int MWG = 128;                 // rows per block (4 waves x 32 rows)

// fragment counts in ws: dW0 (K=128 padded) 16; dW1 8; dbW 2; W0 5h*8=40
// NOTE: these are simultaneously B-frags of W and A-frags of W^T (same lane data).
constexpr int NF_DW0 = 16, NF_DW1 = 8, NF_DBW = 2;
constexpr int NF_LIN = NF_DW0 + NF_DW1 + NF_DBW;     // 26
constexpr int NF_TOT = NF_LIN + 40;                  // 66

__device__ __forceinline__ unsigned short f2bf_rne(float f) {
    union { float f; unsigned u; } v{f};
    unsigned r = v.u + 0x7FFF + ((v.u >> 16) & 1);   // RNE
    return (unsigned short)(r >> 16);
}

// pack two floats -> one VGPR of bf16x2 (RNE) via v_cvt_pk_bf16_f32
__device__ __forceinline__ unsigned pkbf(float a, float b) {
    union { __hip_bfloat162 h; unsigned u; } u;
    u.h = __float22bfloat162_rn(make_float2(a, b));  // .x -> low 16, .y -> high 16
    return u.u;
}

union frag_u { unsigned u[4]; short8 s; };

__device__ __forceinline__ short8 ldfrag(const unsigned short* __restrict__ ws,
                                         int f, int lane) {
    return *(const short8*)(ws + (size_t)(f * 64 + lane) * 8);
}

// ---- pack weights as bf16 MFMA fragments into ws (unchanged, verified) ----
__global__ __launch_bounds__(64) void pack_kernel(
    const float* __restrict__ dW0, const float* __restrict__ dW1,
    const float* __restrict__ dbW, const float* __restrict__ W0,
    unsigned short* __restrict__ ws)
{
    const int f = blockIdx.x;
    const int lane = threadIdx.x;
    const int q = lane >> 4, cl = lane & 15;
    float v[8];
    if (f < NF_DW0) {
        int c = f >> 2, g = f & 3;
        #pragma unroll
        for (int j = 0; j < 8; ++j) {
            int k = c * 32 + q * 8 + j, n = g * 16 + cl;
            v[j] = (k < DIN) ? dW0[k * H + n] : 0.0f;
        }
    } else if (f < NF_DW0 + NF_DW1) {
        int r = f - NF_DW0; int c = r >> 2, g = r & 3;
        #pragma unroll
        for (int j = 0; j < 8; ++j) {
            int k = c * 32 + q * 8 + j, n = g * 16 + cl;
            v[j] = dW1[k * H + n];
        }
    } else if (f < NF_LIN) {
        int c = f - (NF_DW0 + NF_DW1);
        #pragma unroll
        for (int j = 0; j < 8; ++j) {
            int k = c * 32 + q * 8 + j, n = cl;
            v[j] = (n <= G) ? dbW[k * (G + 1) + n] : 0.0f;
        }
    } else {
        int r = f - NF_LIN; int h = r >> 3; r &= 7; int c = r >> 2, g = r & 3;
        #pragma unroll
        for (int j = 0; j < 8; ++j) {
            int k = c * 32 + q * 8 + j, n = g * 16 + cl;
            v[j] = W0[(h * H + k) * H + n];
        }
    }
    short8 s;
    #pragma unroll
    for (int j = 0; j < 8; ++j) s[j] = (short)f2bf_rne(v[j]);
    *(short8*)(ws + (size_t)(f * 64 + lane) * 8) = s;
}

// C-layout (feat-tiles) -> next-layer B-frags, pure cross-lane.
// P[f][w]: packed bf16 pairs of tile f (w=0: rows 0,1; w=1: rows 2,3).
// out[c2][reg]: B-frag regs for K-chunk c2 (K = c2*32 + q*8 + j).
__device__ __forceinline__ void transp(const unsigned P[4][2], int q, int cl,
                                       unsigned out[2][4]) {
    const int sL = (((2 * q) & 3) << 4) | cl;
    const int sH = (((2 * q + 1) & 3) << 4) | cl;
    const bool hi = (q >= 2);
    #pragma unroll
    for (int c2 = 0; c2 < 2; ++c2)
        #pragma unroll
        for (int w = 0; w < 2; ++w) {
            int a0 = __shfl((int)P[2 * c2][w], sL);
            int a1 = __shfl((int)P[2 * c2 + 1][w], sL);
            out[c2][w] = (unsigned)(hi ? a1 : a0);
            int b0 = __shfl((int)P[2 * c2][w], sH);
            int b1 = __shfl((int)P[2 * c2 + 1][w], sH);
            out[c2][2 + w] = (unsigned)(hi ? b1 : b0);
        }
}

// ---- main kernel: fully transposed GEMMs (W^T as A), no LDS, no barriers ----
__global__ __launch_bounds__(256, 4) void drnet_t(
    const float* __restrict__ dosage, const float* __restrict__ x,
    const float* __restrict__ db0, const float* __restrict__ db1,
    const float* __restrict__ dbB,
    const float* __restrict__ tw0, const float* __restrict__ b0,
    const float* __restrict__ W1, const float* __restrict__ tw1,
    const float* __restrict__ b1,
    const unsigned short* __restrict__ wsfrag,
    float* __restrict__ outg, float* __restrict__ outq)
{
    const int tid  = threadIdx.x;
    const int wave = tid >> 6, lane = tid & 63;
    const int q = lane >> 4, cl = lane & 15;
    const int rowbase = blockIdx.x * MWG + wave * 32;   // this wave's 32 rows

    // per-mt batch row for this lane's B-column: rowbase + mt*16 + cl
    float tmt[2]; int bkmt[2];
    #pragma unroll
    for (int mt = 0; mt < 2; ++mt) {
        float t = dosage[rowbase + mt * 16 + cl];
        tmt[mt] = t;
        bkmt[mt] = min(max((int)floorf(t * (float)NH), 0), NH - 1);
    }

    unsigned af[2][2][4];    // h2^T B-frags per mt (reused by density + heads)

    #pragma unroll 1
    for (int mt = 0; mt < 2; ++mt) {
        // ---- x^T B-frags: lane (q,cl) holds x[row cl][c*32+q*8+j] ----
        unsigned xf[4][4];
        const float* xr = x + (size_t)(rowbase + mt * 16 + cl) * DIN;
        #pragma unroll
        for (int c = 0; c < 4; ++c) {
            float f[8];
            if (c < 3) {
                floatx4 u0 = *(const floatx4*)(xr + c * 32 + q * 8);
                floatx4 u1 = *(const floatx4*)(xr + c * 32 + q * 8 + 4);
                f[0]=u0.x; f[1]=u0.y; f[2]=u0.z; f[3]=u0.w;
                f[4]=u1.x; f[5]=u1.y; f[6]=u1.z; f[7]=u1.w;
            } else if (q == 0) {
                floatx4 u0 = *(const floatx4*)(xr + 96);
                f[0]=u0.x; f[1]=u0.y; f[2]=u0.z; f[3]=u0.w;
                f[4]=f[5]=f[6]=f[7]=0.0f;
            } else {
                #pragma unroll
                for (int j = 0; j < 8; ++j) f[j] = 0.0f;
            }
            xf[c][0] = pkbf(f[0], f[1]); xf[c][1] = pkbf(f[2], f[3]);
            xf[c][2] = pkbf(f[4], f[5]); xf[c][3] = pkbf(f[6], f[7]);
        }
        // ---- layer 1: C1 = dW0^T @ x^T  (lane: [feat f*16+4q+r][batch cl]) ----
        floatx4 acc[4];
        #pragma unroll
        for (int f = 0; f < 4; ++f) acc[f] = (floatx4)0.0f;
        #pragma unroll
        for (int c = 0; c < 4; ++c) {
            frag_u b; b.u[0]=xf[c][0]; b.u[1]=xf[c][1]; b.u[2]=xf[c][2]; b.u[3]=xf[c][3];
            #pragma unroll
            for (int f = 0; f < 4; ++f)
                acc[f] = __builtin_amdgcn_mfma_f32_16x16x32_bf16(
                    ldfrag(wsfrag, c * 4 + f, lane), b.s, acc[f], 0, 0, 0);
        }
        unsigned P[4][2];
        #pragma unroll
        for (int f = 0; f < 4; ++f) {
            floatx4 b4 = *(const floatx4*)(db0 + f * 16 + 4 * q);
            float v0 = fmaxf(acc[f][0] + b4[0], 0.0f);
            float v1 = fmaxf(acc[f][1] + b4[1], 0.0f);
            float v2 = fmaxf(acc[f][2] + b4[2], 0.0f);
            float v3 = fmaxf(acc[f][3] + b4[3], 0.0f);
            P[f][0] = pkbf(v0, v1); P[f][1] = pkbf(v2, v3);
        }
        unsigned hf[2][4];
        transp(P, q, cl, hf);                       // h1^T B-frags

        // ---- layer 2: C2 = dW1^T @ h1^T ----
        #pragma unroll
        for (int f = 0; f < 4; ++f) acc[f] = (floatx4)0.0f;
        #pragma unroll
        for (int c2 = 0; c2 < 2; ++c2) {
            frag_u b; b.u[0]=hf[c2][0]; b.u[1]=hf[c2][1]; b.u[2]=hf[c2][2]; b.u[3]=hf[c2][3];
            #pragma unroll
            for (int f = 0; f < 4; ++f)
                acc[f] = __builtin_amdgcn_mfma_f32_16x16x32_bf16(
                    ldfrag(wsfrag, NF_DW0 + c2 * 4 + f, lane), b.s, acc[f], 0, 0, 0);
        }
        #pragma unroll
        for (int f = 0; f < 4; ++f) {
            floatx4 b4 = *(const floatx4*)(db1 + f * 16 + 4 * q);
            float v0 = fmaxf(acc[f][0] + b4[0], 0.0f);
            float v1 = fmaxf(acc[f][1] + b4[1], 0.0f);
            float v2 = fmaxf(acc[f][2] + b4[2], 0.0f);
            float v3 = fmaxf(acc[f][3] + b4[3], 0.0f);
            P[f][0] = pkbf(v0, v1); P[f][1] = pkbf(v2, v3);
        }
        transp(P, q, cl, af[mt]);                   // h2^T B-frags

        // ---- density: C4 = dbW^T @ h2^T; softmax over grid (cross-lane) ----
        floatx4 accd = (floatx4)0.0f;
        #pragma unroll
        for (int c2 = 0; c2 < 2; ++c2) {
            frag_u b; b.u[0]=af[mt][c2][0]; b.u[1]=af[mt][c2][1];
            b.u[2]=af[mt][c2][2]; b.u[3]=af[mt][c2][3];
            accd = __builtin_amdgcn_mfma_f32_16x16x32_bf16(
                ldfrag(wsfrag, NF_DW0 + NF_DW1 + c2, lane), b.s, accd, 0, 0, 0);
        }
        float e[4];
        #pragma unroll
        for (int r = 0; r < 4; ++r) {
            int gi = 4 * q + r;
            e[r] = (gi <= G) ? __expf(accd[r] + dbB[gi]) : 0.0f;  // logits tiny: no max-sub
        }
        float s = (e[0] + e[1]) + (e[2] + e[3]);
        s += __shfl_xor(s, 16); s += __shfl_xor(s, 32);
        const float t  = tmt[mt];
        const float tB = t * (float)G;
        const float U  = ceilf(tB);
        const float inter = 1.0f - (U - tB);
        int Ui = (int)U; int Li = Ui - 1; if (Li < 0) Li = 0;
        float l01 = (Li & 1) ? e[1] : e[0], l23 = (Li & 1) ? e[3] : e[2];
        float vL  = (Li & 2) ? l23 : l01;
        float u01 = (Ui & 1) ? e[1] : e[0], u23 = (Ui & 1) ? e[3] : e[2];
        float vU  = (Ui & 2) ? u23 : u01;
        float pL = __shfl(vL, ((Li >> 2) << 4) + cl);
        float pU = __shfl(vU, ((Ui >> 2) << 4) + cl);
        float gv = (pL + (pU - pL) * inter) / s;
        if (q == 0) outg[rowbase + mt * 16 + cl] = gv;
    }

    // ---- heads: C3 = W0[h]^T @ h2^T per h; epilogue per lane, quad-reduce ----
    float Q[2] = {0.0f, 0.0f};
    #pragma unroll 1
    for (int h = 0; h < NH; ++h) {
        short8 wf[8];
        #pragma unroll
        for (int i = 0; i < 8; ++i) wf[i] = ldfrag(wsfrag, NF_LIN + h * 8 + i, lane);
        #pragma unroll
        for (int mt = 0; mt < 2; ++mt) {
            floatx4 a3[4];
            #pragma unroll
            for (int f = 0; f < 4; ++f) a3[f] = (floatx4)0.0f;
            #pragma unroll
            for (int c2 = 0; c2 < 2; ++c2) {
                frag_u b; b.u[0]=af[mt][c2][0]; b.u[1]=af[mt][c2][1];
                b.u[2]=af[mt][c2][2]; b.u[3]=af[mt][c2][3];
                #pragma unroll
                for (int f = 0; f < 4; ++f)
                    a3[f] = __builtin_amdgcn_mfma_f32_16x16x32_bf16(
                        wf[c2 * 4 + f], b.s, a3[f], 0, 0, 0);
            }
            float part = 0.0f;
            #pragma unroll
            for (int f = 0; f < 4; ++f) {
                const int off = h * H + f * 16 + 4 * q;
                floatx4 tw4 = *(const floatx4*)(tw0 + off);
                floatx4 b04 = *(const floatx4*)(b0 + off);
                floatx4 w14 = *(const floatx4*)(W1 + off);
                #pragma unroll
                for (int r = 0; r < 4; ++r) {
                    float v = a3[f][r] + tmt[mt] * tw4[r] + b04[r];
                    part = fmaf(fmaxf(v, 0.0f), w14[r], part);
                }
            }
            part += __shfl_xor(part, 16); part += __shfl_xor(part, 32);
            Q[mt] += (bkmt[mt] == h) ? part : 0.0f;
        }
    }
    #pragma unroll
    for (int mt = 0; mt < 2; ++mt) {
        const int h = bkmt[mt];
        float qv = Q[mt] + tmt[mt] * tw1[h] + b1[h];
        if (q == 0) outq[rowbase + mt * 16 + cl] = qv;
    }
}

extern "C" void kernel_launch(void* const* d_in, const int* in_sizes, int n_in,
                              void* d_out, int out_size, void* d_ws, size_t ws_size,
                              hipStream_t stream) {
    const float* dosage = (const float*)d_in[0];
    const float* x      = (const float*)d_in[1];
    const float* dW0    = (const float*)d_in[2];
    const float* db0    = (const float*)d_in[3];
    const float* dW1    = (const float*)d_in[4];
    const float* db1    = (const float*)d_in[5];
    const float* dbW    = (const float*)d_in[6];
    const float* dbB    = (const float*)d_in[7];
    const float* W0     = (const float*)d_in[8];
    const float* tw0    = (const float*)d_in[9];
    const float* b0     = (const float*)d_in[10];
    const float* W1     = (const float*)d_in[11];
    const float* tw1    = (const float*)d_in[12];
    const float* b1     = (const float*)d_in[13];

    const int Btot = in_sizes[0];
    float* outg = (float*)d_out;
    float* outq = outg + Btot;
    unsigned short* wsfrag = (unsigned short*)d_ws;

    pack_kernel<<<NF_TOT, 64, 0, stream>>>(dW0, dW1, dbW, W0, wsfrag);
    drnet_t<<<Btot / MWG, 256, 0, stream>>>(dosage, x, db0, db1, dbB,
                                            tw0, b0, W1, tw1, b1,
                                            wsfrag, outg, outq);
}

// Round 11
// 245.628 us; speedup vs baseline: 1.1115x; 1.1115x over previous
//
#include <hip/hip_runtime.h>
#include <hip/hip_bf16.h>

typedef __attribute__((ext_vector_type(8))) short  short8;
typedef __attribute__((ext_vector_type(4))) float  floatx4;

constexpr int DIN = 100;
constexpr int H   = 64;
constexpr int G   = 10;
constexpr int NH  = 5;
constexpr int MWG = 128;                 // rows per block (4 waves x 32 rows)

// fragment counts in ws: dW0 (K=128 padded) 16; dW1 8; dbW 2; W0 5h*8=40
// NOTE: these are simultaneously B-frags of W and A-frags of W^T (same lane data).
constexpr int NF_DW0 = 16, NF_DW1 = 8, NF_DBW = 2;
constexpr int NF_LIN = NF_DW0 + NF_DW1 + NF_DBW;     // 26
constexpr int NF_TOT = NF_LIN + 40;                  // 66

__device__ __forceinline__ unsigned short f2bf_rne(float f) {
    union { float f; unsigned u; } v{f};
    unsigned r = v.u + 0x7FFF + ((v.u >> 16) & 1);   // RNE
    return (unsigned short)(r >> 16);
}

// pack two floats -> one VGPR of bf16x2 (RNE) via v_cvt_pk_bf16_f32
__device__ __forceinline__ unsigned pkbf(float a, float b) {
    union { __hip_bfloat162 h; unsigned u; } u;
    u.h = __float22bfloat162_rn(make_float2(a, b));  // .x -> low 16, .y -> high 16
    return u.u;
}

union frag_u { unsigned u[4]; short8 s; };

__device__ __forceinline__ short8 ldfrag(const unsigned short* __restrict__ ws,
                                         int f, int lane) {
    return *(const short8*)(ws + (size_t)(f * 64 + lane) * 8);
}

// ---- pack weights as bf16 MFMA fragments into ws (unchanged, verified) ----
__global__ __launch_bounds__(64) void pack_kernel(
    const float* __restrict__ dW0, const float* __restrict__ dW1,
    const float* __restrict__ dbW, const float* __restrict__ W0,
    unsigned short* __restrict__ ws)
{
    const int f = blockIdx.x;
    const int lane = threadIdx.x;
    const int q = lane >> 4, cl = lane & 15;
    float v[8];
    if (f < NF_DW0) {
        int c = f >> 2, g = f & 3;
        #pragma unroll
        for (int j = 0; j < 8; ++j) {
            int k = c * 32 + q * 8 + j, n = g * 16 + cl;
            v[j] = (k < DIN) ? dW0[k * H + n] : 0.0f;
        }
    } else if (f < NF_DW0 + NF_DW1) {
        int r = f - NF_DW0; int c = r >> 2, g = r & 3;
        #pragma unroll
        for (int j = 0; j < 8; ++j) {
            int k = c * 32 + q * 8 + j, n = g * 16 + cl;
            v[j] = dW1[k * H + n];
        }
    } else if (f < NF_LIN) {
        int c = f - (NF_DW0 + NF_DW1);
        #pragma unroll
        for (int j = 0; j < 8; ++j) {
            int k = c * 32 + q * 8 + j, n = cl;
            v[j] = (n <= G) ? dbW[k * (G + 1) + n] : 0.0f;
        }
    } else {
        int r = f - NF_LIN; int h = r >> 3; r &= 7; int c = r >> 2, g = r & 3;
        #pragma unroll
        for (int j = 0; j < 8; ++j) {
            int k = c * 32 + q * 8 + j, n = g * 16 + cl;
            v[j] = W0[(h * H + k) * H + n];
        }
    }
    short8 s;
    #pragma unroll
    for (int j = 0; j < 8; ++j) s[j] = (short)f2bf_rne(v[j]);
    *(short8*)(ws + (size_t)(f * 64 + lane) * 8) = s;
}

// C-layout (feat-tiles) -> next-layer B-frags, pure cross-lane.
__device__ __forceinline__ void transp(const unsigned P[4][2], int q, int cl,
                                       unsigned out[2][4]) {
    const int sL = (((2 * q) & 3) << 4) | cl;
    const int sH = (((2 * q + 1) & 3) << 4) | cl;
    const bool hi = (q >= 2);
    #pragma unroll
    for (int c2 = 0; c2 < 2; ++c2)
        #pragma unroll
        for (int w = 0; w < 2; ++w) {
            int a0 = __shfl((int)P[2 * c2][w], sL);
            int a1 = __shfl((int)P[2 * c2 + 1][w], sL);
            out[c2][w] = (unsigned)(hi ? a1 : a0);
            int b0 = __shfl((int)P[2 * c2][w], sH);
            int b1 = __shfl((int)P[2 * c2 + 1][w], sH);
            out[c2][2 + w] = (unsigned)(hi ? b1 : b0);
        }
}

// one m-tile: x -> layer1 -> layer2 -> density (+g write); af = h2^T B-frags.
// All arrays statically indexed -> stays in VGPRs (R10's scratch-spill fix).
__device__ __forceinline__ void stage_mt(
    const float* __restrict__ xr, float t, int q, int cl, int lane,
    const float* __restrict__ db0, const float* __restrict__ db1,
    const float* __restrict__ dbB,
    const unsigned short* __restrict__ wsfrag,
    unsigned af[2][4], float* __restrict__ gaddr)
{
    // ---- x^T B-frags ----
    unsigned xf[4][4];
    #pragma unroll
    for (int c = 0; c < 4; ++c) {
        float f[8];
        if (c < 3) {
            floatx4 u0 = *(const floatx4*)(xr + c * 32 + q * 8);
            floatx4 u1 = *(const floatx4*)(xr + c * 32 + q * 8 + 4);
            f[0]=u0.x; f[1]=u0.y; f[2]=u0.z; f[3]=u0.w;
            f[4]=u1.x; f[5]=u1.y; f[6]=u1.z; f[7]=u1.w;
        } else if (q == 0) {
            floatx4 u0 = *(const floatx4*)(xr + 96);
            f[0]=u0.x; f[1]=u0.y; f[2]=u0.z; f[3]=u0.w;
            f[4]=f[5]=f[6]=f[7]=0.0f;
        } else {
            #pragma unroll
            for (int j = 0; j < 8; ++j) f[j] = 0.0f;
        }
        xf[c][0] = pkbf(f[0], f[1]); xf[c][1] = pkbf(f[2], f[3]);
        xf[c][2] = pkbf(f[4], f[5]); xf[c][3] = pkbf(f[6], f[7]);
    }
    // ---- layer 1: C1 = dW0^T @ x^T ----
    floatx4 acc[4];
    #pragma unroll
    for (int f = 0; f < 4; ++f) acc[f] = (floatx4)0.0f;
    #pragma unroll
    for (int c = 0; c < 4; ++c) {
        frag_u b; b.u[0]=xf[c][0]; b.u[1]=xf[c][1]; b.u[2]=xf[c][2]; b.u[3]=xf[c][3];
        #pragma unroll
        for (int f = 0; f < 4; ++f)
            acc[f] = __builtin_amdgcn_mfma_f32_16x16x32_bf16(
                ldfrag(wsfrag, c * 4 + f, lane), b.s, acc[f], 0, 0, 0);
    }
    unsigned P[4][2];
    #pragma unroll
    for (int f = 0; f < 4; ++f) {
        floatx4 b4 = *(const floatx4*)(db0 + f * 16 + 4 * q);
        float v0 = fmaxf(acc[f][0] + b4[0], 0.0f);
        float v1 = fmaxf(acc[f][1] + b4[1], 0.0f);
        float v2 = fmaxf(acc[f][2] + b4[2], 0.0f);
        float v3 = fmaxf(acc[f][3] + b4[3], 0.0f);
        P[f][0] = pkbf(v0, v1); P[f][1] = pkbf(v2, v3);
    }
    unsigned hf[2][4];
    transp(P, q, cl, hf);                       // h1^T B-frags

    // ---- layer 2: C2 = dW1^T @ h1^T ----
    #pragma unroll
    for (int f = 0; f < 4; ++f) acc[f] = (floatx4)0.0f;
    #pragma unroll
    for (int c2 = 0; c2 < 2; ++c2) {
        frag_u b; b.u[0]=hf[c2][0]; b.u[1]=hf[c2][1]; b.u[2]=hf[c2][2]; b.u[3]=hf[c2][3];
        #pragma unroll
        for (int f = 0; f < 4; ++f)
            acc[f] = __builtin_amdgcn_mfma_f32_16x16x32_bf16(
                ldfrag(wsfrag, NF_DW0 + c2 * 4 + f, lane), b.s, acc[f], 0, 0, 0);
    }
    #pragma unroll
    for (int f = 0; f < 4; ++f) {
        floatx4 b4 = *(const floatx4*)(db1 + f * 16 + 4 * q);
        float v0 = fmaxf(acc[f][0] + b4[0], 0.0f);
        float v1 = fmaxf(acc[f][1] + b4[1], 0.0f);
        float v2 = fmaxf(acc[f][2] + b4[2], 0.0f);
        float v3 = fmaxf(acc[f][3] + b4[3], 0.0f);
        P[f][0] = pkbf(v0, v1); P[f][1] = pkbf(v2, v3);
    }
    transp(P, q, cl, af);                       // h2^T B-frags

    // ---- density: C4 = dbW^T @ h2^T; softmax + interp (cross-lane) ----
    floatx4 accd = (floatx4)0.0f;
    #pragma unroll
    for (int c2 = 0; c2 < 2; ++c2) {
        frag_u b; b.u[0]=af[c2][0]; b.u[1]=af[c2][1]; b.u[2]=af[c2][2]; b.u[3]=af[c2][3];
        accd = __builtin_amdgcn_mfma_f32_16x16x32_bf16(
            ldfrag(wsfrag, NF_DW0 + NF_DW1 + c2, lane), b.s, accd, 0, 0, 0);
    }
    float e[4];
    #pragma unroll
    for (int r = 0; r < 4; ++r) {
        int gi = 4 * q + r;
        e[r] = (gi <= G) ? __expf(accd[r] + dbB[gi]) : 0.0f;  // logits tiny: no max-sub
    }
    float s = (e[0] + e[1]) + (e[2] + e[3]);
    s += __shfl_xor(s, 16); s += __shfl_xor(s, 32);
    const float tB = t * (float)G;
    const float U  = ceilf(tB);
    const float inter = 1.0f - (U - tB);
    int Ui = (int)U; int Li = Ui - 1; if (Li < 0) Li = 0;
    float l01 = (Li & 1) ? e[1] : e[0], l23 = (Li & 1) ? e[3] : e[2];
    float vL  = (Li & 2) ? l23 : l01;
    float u01 = (Ui & 1) ? e[1] : e[0], u23 = (Ui & 1) ? e[3] : e[2];
    float vU  = (Ui & 2) ? u23 : u01;
    float pL = __shfl(vL, ((Li >> 2) << 4) + cl);
    float pU = __shfl(vU, ((Ui >> 2) << 4) + cl);
    float gv = (pL + (pU - pL) * inter) / s;
    if (q == 0) *gaddr = gv;
}

// ---- main kernel: fully transposed GEMMs (W^T as A), no LDS, no barriers ----
__global__ __launch_bounds__(256, 4) void drnet_t(
    const float* __restrict__ dosage, const float* __restrict__ x,
    const float* __restrict__ db0, const float* __restrict__ db1,
    const float* __restrict__ dbB,
    const float* __restrict__ tw0, const float* __restrict__ b0,
    const float* __restrict__ W1, const float* __restrict__ tw1,
    const float* __restrict__ b1,
    const unsigned short* __restrict__ wsfrag,
    float* __restrict__ outg, float* __restrict__ outq)
{
    const int tid  = threadIdx.x;
    const int wave = tid >> 6, lane = tid & 63;
    const int q = lane >> 4, cl = lane & 15;
    const int rowbase = blockIdx.x * MWG + wave * 32;   // this wave's 32 rows

    const float t0 = dosage[rowbase + cl];
    const float t1 = dosage[rowbase + 16 + cl];
    const int bk0 = min(max((int)floorf(t0 * (float)NH), 0), NH - 1);
    const int bk1 = min(max((int)floorf(t1 * (float)NH), 0), NH - 1);

    unsigned af0[2][4], af1[2][4];    // h2^T B-frags (static names -> VGPRs)
    stage_mt(x + (size_t)(rowbase + cl) * DIN,      t0, q, cl, lane,
             db0, db1, dbB, wsfrag, af0, outg + rowbase + cl);
    stage_mt(x + (size_t)(rowbase + 16 + cl) * DIN, t1, q, cl, lane,
             db0, db1, dbB, wsfrag, af1, outg + rowbase + 16 + cl);

    // ---- heads: C3 = W0[h]^T @ h2^T per h; epilogue per lane, quad-reduce ----
    float Q0 = 0.0f, Q1 = 0.0f;
    #pragma unroll 1
    for (int h = 0; h < NH; ++h) {
        short8 wf[8];
        #pragma unroll
        for (int i = 0; i < 8; ++i) wf[i] = ldfrag(wsfrag, NF_LIN + h * 8 + i, lane);

        floatx4 a30[4], a31[4];
        #pragma unroll
        for (int f = 0; f < 4; ++f) { a30[f] = (floatx4)0.0f; a31[f] = (floatx4)0.0f; }
        #pragma unroll
        for (int c2 = 0; c2 < 2; ++c2) {
            frag_u b0f; b0f.u[0]=af0[c2][0]; b0f.u[1]=af0[c2][1];
            b0f.u[2]=af0[c2][2]; b0f.u[3]=af0[c2][3];
            frag_u b1f; b1f.u[0]=af1[c2][0]; b1f.u[1]=af1[c2][1];
            b1f.u[2]=af1[c2][2]; b1f.u[3]=af1[c2][3];
            #pragma unroll
            for (int f = 0; f < 4; ++f) {
                a30[f] = __builtin_amdgcn_mfma_f32_16x16x32_bf16(
                    wf[c2 * 4 + f], b0f.s, a30[f], 0, 0, 0);
                a31[f] = __builtin_amdgcn_mfma_f32_16x16x32_bf16(
                    wf[c2 * 4 + f], b1f.s, a31[f], 0, 0, 0);
            }
        }
        float p0 = 0.0f, p1 = 0.0f;
        #pragma unroll
        for (int f = 0; f < 4; ++f) {
            const int off = h * H + f * 16 + 4 * q;
            floatx4 tw4 = *(const floatx4*)(tw0 + off);
            floatx4 b04 = *(const floatx4*)(b0 + off);
            floatx4 w14 = *(const floatx4*)(W1 + off);
            #pragma unroll
            for (int r = 0; r < 4; ++r) {
                float v0 = a30[f][r] + t0 * tw4[r] + b04[r];
                p0 = fmaf(fmaxf(v0, 0.0f), w14[r], p0);
                float v1 = a31[f][r] + t1 * tw4[r] + b04[r];
                p1 = fmaf(fmaxf(v1, 0.0f), w14[r], p1);
            }
        }
        p0 += __shfl_xor(p0, 16); p0 += __shfl_xor(p0, 32);
        p1 += __shfl_xor(p1, 16); p1 += __shfl_xor(p1, 32);
        Q0 += (bk0 == h) ? p0 : 0.0f;
        Q1 += (bk1 == h) ? p1 : 0.0f;
    }
    if (q == 0) {
        outq[rowbase + cl]      = Q0 + t0 * tw1[bk0] + b1[bk0];
        outq[rowbase + 16 + cl] = Q1 + t1 * tw1[bk1] + b1[bk1];
    }
}

extern "C" void kernel_launch(void* const* d_in, const int* in_sizes, int n_in,
                              void* d_out, int out_size, void* d_ws, size_t ws_size,
                              hipStream_t stream) {
    const float* dosage = (const float*)d_in[0];
    const float* x      = (const float*)d_in[1];
    const float* dW0    = (const float*)d_in[2];
    const float* db0    = (const float*)d_in[3];
    const float* dW1    = (const float*)d_in[4];
    const float* db1    = (const float*)d_in[5];
    const float* dbW    = (const float*)d_in[6];
    const float* dbB    = (const float*)d_in[7];
    const float* W0     = (const float*)d_in[8];
    const float* tw0    = (const float*)d_in[9];
    const float* b0     = (const float*)d_in[10];
    const float* W1     = (const float*)d_in[11];
    const float* tw1    = (const float*)d_in[12];
    const float* b1     = (const float*)d_in[13];

    const int Btot = in_sizes[0];
    float* outg = (float*)d_out;
    float* outq = outg + Btot;
    unsigned short* wsfrag = (unsigned short*)d_ws;

    pack_kernel<<<NF_TOT, 64, 0, stream>>>(dW0, dW1, dbW, W0, wsfrag);
    drnet_t<<<Btot / MWG, 256, 0, stream>>>(dosage, x, db0, db1, dbB,
                                            tw0, b0, W1, tw1, b1,
                                            wsfrag, outg, outq);
}